// Round 3
// baseline (3758.020 us; speedup 1.0000x reference)
//
#include <hip/hip_runtime.h>
#include <hip/hip_bf16.h>
#include <cstddef>
#include <cstdint>
#include <math.h>

typedef __hip_bfloat16 bf16;

#define DEV __device__ __forceinline__
DEV float bff(bf16 x){ return __bfloat162float(x); }
DEV bf16 fbf(float x){ return __float2bfloat16(x); }
DEV float lr01(float x){ return x>0.f? x : 0.1f*x; }
DEV float lr02(float x){ return x>0.f? x : 0.2f*x; }
DEV float sigm(float x){ return 1.f/(1.f+__expf(-x)); }
DEV float tanhe(float x){ float a=fabsf(x); float e=__expf(-2.f*a); float t=(1.f-e)/(1.f+e); return x<0.f? -t : t; }
DEV void stout(void* out, int isf, size_t i, float v){
  if (isf) ((float*)out)[i] = v; else ((bf16*)out)[i] = fbf(v);
}

// problem constants
#define NBATCH 2048
#define TSEQ 16
#define KNB 12
#define NGRP 32768          // TSEQ*NBATCH groups
#define NNODES 425984       // NGRP*13
#define NBK 24576           // NBATCH*KNB
#define NTOUT 25

// ---------------- dtype detect + convert ----------------
__global__ __launch_bounds__(256) void detect_k(const uint32_t* __restrict__ x, int* __restrict__ flag) {
  __shared__ int cnt;
  if (threadIdx.x == 0) cnt = 0;
  __syncthreads();
  float v = __uint_as_float(x[threadIdx.x]);
  float a = fabsf(v);
  if (a > 1e-12f && a < 100.f) atomicAdd(&cnt, 1);
  __syncthreads();
  if (threadIdx.x == 0) *flag = (cnt >= 128) ? 1 : 0;
}

#define NCVT 55
struct CvtArgs {
  const void* src[NCVT];
  unsigned off[NCVT];
  unsigned cnt[NCVT];
};

__global__ __launch_bounds__(256) void cvt_k(CvtArgs a, float* __restrict__ dst,
                                             const int* __restrict__ flag, unsigned total) {
  const int isf = *flag;
  for (size_t e = (size_t)blockIdx.x*256 + threadIdx.x; e < total; e += (size_t)gridDim.x*256) {
    int lo = 0, hi = NCVT-1;
    while (lo < hi) { int mid = (lo+hi+1)>>1; if ((size_t)a.off[mid] <= e) lo = mid; else hi = mid-1; }
    unsigned r = (unsigned)(e - a.off[lo]);
    float v = isf ? ((const float*)a.src[lo])[r] : bff(((const bf16*)a.src[lo])[r]);
    dst[e] = v;
  }
}

// ---------------- GAT (bf16 activations, f32 weights) ----------------
__global__ __launch_bounds__(256) void ip_emb_k(const float* __restrict__ x, const float* __restrict__ W,
                                                const float* __restrict__ b, bf16* __restrict__ h0) {
  size_t idx = (size_t)blockIdx.x*256 + threadIdx.x;   // NNODES*32
  int f = (int)(idx & 31); size_t v = idx >> 5;
  float acc = b[f];
  #pragma unroll
  for (int k = 0; k < 4; k++) acc += x[v*4+k] * W[f*4+k];
  h0[idx] = fbf(lr01(acc));
}

template<int IN, int OUT>
__global__ __launch_bounds__(256) void dense_bf_k(const bf16* __restrict__ in, const float* __restrict__ W,
                                                  bf16* __restrict__ out) {
  size_t idx = (size_t)blockIdx.x*256 + threadIdx.x;   // NNODES*OUT
  int f = (int)(idx % OUT); size_t v = idx / OUT;
  const bf16* row = in + v*IN;
  const float* wr = W + (size_t)f*IN;
  float acc = 0.f;
  #pragma unroll
  for (int k = 0; k < IN; k++) acc += bff(row[k])*wr[k];
  out[idx] = fbf(acc);
}

template<int F>
__global__ __launch_bounds__(256) void esed_bf_k(const bf16* __restrict__ xw, const float* __restrict__ as_,
                                                 const float* __restrict__ ad_, float* __restrict__ esed) {
  size_t v = (size_t)blockIdx.x*256 + threadIdx.x;     // NNODES
  const bf16* row = xw + v*F;
  float es = 0.f, ed = 0.f;
  #pragma unroll
  for (int k = 0; k < F; k++) { float h = bff(row[k]); es += h*as_[k]; ed += h*ad_[k]; }
  esed[v*2] = es; esed[v*2+1] = ed;
}

// per-group softmax alphas. alph[g][40]: [0..12] ego-incoming, [13+2(j-1)] ego->nbr_j, [14+2(j-1)] nbr_j self
__global__ __launch_bounds__(256) void alpha_k(const float* __restrict__ esed, float* __restrict__ alph) {
  int g = blockIdx.x*256 + threadIdx.x;                // NGRP
  size_t base = (size_t)g*13;
  float esv[13], edv[13];
  #pragma unroll
  for (int i = 0; i < 13; i++) { esv[i] = esed[(base+i)*2]; edv[i] = esed[(base+i)*2+1]; }
  float* o = alph + (size_t)g*40;
  float e[13]; float m = -1e30f;
  #pragma unroll
  for (int i = 0; i < 13; i++) { float z = lr02(esv[i] + edv[0]); e[i] = z; m = fmaxf(m, z); }
  float den = 0.f;
  #pragma unroll
  for (int i = 0; i < 13; i++) { e[i] = __expf(e[i]-m); den += e[i]; }
  float inv = 1.f/den;
  #pragma unroll
  for (int i = 0; i < 13; i++) o[i] = e[i]*inv;
  #pragma unroll
  for (int j = 1; j <= 12; j++) {
    float z0 = lr02(esv[0] + edv[j]);
    float z1 = lr02(esv[j] + edv[j]);
    float mm = fmaxf(z0, z1);
    float a0 = __expf(z0-mm), a1 = __expf(z1-mm);
    float s = 1.f/(a0+a1);
    o[13 + 2*(j-1)] = a0*s;
    o[14 + 2*(j-1)] = a1*s;
  }
}

template<int F>
__global__ __launch_bounds__(256) void agg_bf_k(const bf16* __restrict__ xw, const float* __restrict__ alph,
                                                const float* __restrict__ bias, bf16* __restrict__ out) {
  size_t idx = (size_t)blockIdx.x*256 + threadIdx.x;   // NNODES*F
  int f = (int)(idx % F);
  size_t vn = idx / F;
  int node = (int)(vn % 13);
  size_t g = vn / 13;
  size_t base = g*13;
  const float* al = alph + g*40;
  float acc = 0.f;
  if (node == 0) {
    #pragma unroll
    for (int i = 0; i < 13; i++) acc += al[i] * bff(xw[(base+i)*F + f]);
  } else {
    float a0 = al[13 + 2*(node-1)], a1 = al[14 + 2*(node-1)];
    acc = a0*bff(xw[base*F + f]) + a1*bff(xw[(base+node)*F + f]);
  }
  out[idx] = fbf(lr01(acc + bias[f]));
}

// ---------------- fused embed + GEMM: C[m][n] = x_row(m) @ W[n][:]  K=144, N=256 ----------------
template<bool NBR>
__global__ __launch_bounds__(256) void gemm_embed_k(
    const float* __restrict__ p_in, const float* __restrict__ v_in,
    const float* __restrict__ di_in, const float* __restrict__ l_in,
    const bf16* __restrict__ h2,
    const float* __restrict__ posW, const float* __restrict__ posb,
    const float* __restrict__ vaW, const float* __restrict__ vab,
    const float* __restrict__ disW, const float* __restrict__ disb,
    const float* __restrict__ laneW, const float* __restrict__ laneb,
    const float* __restrict__ W, float* __restrict__ C, int t_fixed) {
  __shared__ __align__(16) float As[8][132];
  __shared__ __align__(16) float Bs[8][132];
  const int tid = threadIdx.x;
  const int bm = blockIdx.x * 128, bn = blockIdx.y * 128;
  const int tx = tid & 15, ty = tid >> 4;
  const int NROW = NBR ? NBK : NBATCH;
  float acc[8][8];
  #pragma unroll
  for (int i = 0; i < 8; i++)
    #pragma unroll
    for (int j = 0; j < 8; j++) acc[i][j] = 0.f;
  for (int k0 = 0; k0 < 144; k0 += 8) {
    #pragma unroll
    for (int i = 0; i < 4; i++) {
      int lin = tid + 256*i;
      int kk = lin & 7, mm = lin >> 3;
      int m = bm + mm;
      int f = k0 + kk;
      int t, n2;
      if (NBR) { t = t_fixed; n2 = m; } else { t = m >> 11; n2 = m & 2047; }
      size_t rn = (size_t)t*NROW + n2;
      float val;
      if (f < 32) {
        val = lr01(p_in[rn*2]*posW[f*2] + p_in[rn*2+1]*posW[f*2+1] + posb[f]);
      } else if (f < 64) {
        int ff = f-32;
        val = lr01(v_in[rn*2]*vaW[ff*2] + v_in[rn*2+1]*vaW[ff*2+1] + vab[ff]);
      } else if (f < 80) {
        int ff = f-64;
        val = lr01(di_in[rn]*disW[ff] + disb[ff]);
      } else if (f < 112) {
        int ff = f-80;
        val = lr01(l_in[rn*2]*laneW[ff*2] + l_in[rn*2+1]*laneW[ff*2+1] + laneb[ff]);
      } else {
        int b = NBR ? (n2 / KNB) : n2;
        int node_off = NBR ? (1 + n2 % KNB) : 0;
        size_t node = ((size_t)t*NBATCH + b)*13 + node_off;
        val = bff(h2[node*32 + (f-112)]);
      }
      As[kk][mm] = val;
      Bs[kk][mm] = W[(size_t)(bn+mm)*144 + f];
    }
    __syncthreads();
    #pragma unroll
    for (int kk = 0; kk < 8; kk++) {
      float4 a0 = *(const float4*)&As[kk][ty*4];
      float4 a1 = *(const float4*)&As[kk][64+ty*4];
      float4 b0 = *(const float4*)&Bs[kk][tx*4];
      float4 b1 = *(const float4*)&Bs[kk][64+tx*4];
      float av[8] = {a0.x,a0.y,a0.z,a0.w,a1.x,a1.y,a1.z,a1.w};
      float bv[8] = {b0.x,b0.y,b0.z,b0.w,b1.x,b1.y,b1.z,b1.w};
      #pragma unroll
      for (int i = 0; i < 8; i++)
        #pragma unroll
        for (int j = 0; j < 8; j++) acc[i][j] += av[i]*bv[j];
    }
    __syncthreads();
  }
  #pragma unroll
  for (int i = 0; i < 8; i++) {
    int m = bm + (i>>2)*64 + ty*4 + (i&3);
    #pragma unroll
    for (int jh = 0; jh < 2; jh++) {
      float4 v = make_float4(acc[i][jh*4+0], acc[i][jh*4+1], acc[i][jh*4+2], acc[i][jh*4+3]);
      *(float4*)&C[(size_t)m*256 + bn + jh*64 + tx*4] = v;
    }
  }
}

// ---------------- GEMM (dec projection): C[m][n] = A[m][:] @ W[n][:]  A bf16, W f32 ----------------
__global__ __launch_bounds__(256) void gemm_bt(const bf16* __restrict__ A, const float* __restrict__ W,
                                               float* __restrict__ C, int M, int N, int Kd) {
  __shared__ __align__(16) float As[8][132];
  __shared__ __align__(16) float Bs[8][132];
  const int tid = threadIdx.x;
  const int bm = blockIdx.x * 128, bn = blockIdx.y * 128;
  const int tx = tid & 15, ty = tid >> 4;
  float acc[8][8];
  #pragma unroll
  for (int i = 0; i < 8; i++)
    #pragma unroll
    for (int j = 0; j < 8; j++) acc[i][j] = 0.f;
  for (int k0 = 0; k0 < Kd; k0 += 8) {
    #pragma unroll
    for (int i = 0; i < 4; i++) {
      int lin = tid + 256*i;
      int kk = lin & 7, mm = lin >> 3;
      int gk = k0 + kk;
      As[kk][mm] = (gk < Kd) ? bff(A[(size_t)(bm+mm)*Kd + gk]) : 0.f;
      Bs[kk][mm] = (gk < Kd) ? W[(size_t)(bn+mm)*Kd + gk] : 0.f;
    }
    __syncthreads();
    #pragma unroll
    for (int kk = 0; kk < 8; kk++) {
      float4 a0 = *(const float4*)&As[kk][ty*4];
      float4 a1 = *(const float4*)&As[kk][64+ty*4];
      float4 b0 = *(const float4*)&Bs[kk][tx*4];
      float4 b1 = *(const float4*)&Bs[kk][64+tx*4];
      float av[8] = {a0.x,a0.y,a0.z,a0.w,a1.x,a1.y,a1.z,a1.w};
      float bv[8] = {b0.x,b0.y,b0.z,b0.w,b1.x,b1.y,b1.z,b1.w};
      #pragma unroll
      for (int i = 0; i < 8; i++)
        #pragma unroll
        for (int j = 0; j < 8; j++) acc[i][j] += av[i]*bv[j];
    }
    __syncthreads();
  }
  #pragma unroll
  for (int i = 0; i < 8; i++) {
    int m = bm + (i>>2)*64 + ty*4 + (i&3);
    #pragma unroll
    for (int jh = 0; jh < 2; jh++) {
      float4 v = make_float4(acc[i][jh*4+0], acc[i][jh*4+1], acc[i][jh*4+2], acc[i][jh*4+3]);
      *(float4*)&C[(size_t)m*N + bn + jh*64 + tx*4] = v;
    }
  }
}

// ---------------- monolithic LSTM H=64 (ta) ----------------
__global__ __launch_bounds__(256) void lstm64_k(const float* __restrict__ XW, const float* __restrict__ Whh,
    const float* __restrict__ bih, const float* __restrict__ bhh, int N, int steps,
    float* __restrict__ h_all, float* __restrict__ h_final) {
  __shared__ __align__(16) float h_s[16][64];
  __shared__ __align__(16) float gates[16][256];
  const int j = threadIdx.x;
  const int r0 = blockIdx.x * 16;
  float w[64];
  #pragma unroll
  for (int k = 0; k < 64; k++) w[k] = Whh[(size_t)j*64 + k];
  const float bj = bih[j] + bhh[j];
  for (int i = j; i < 16*64; i += 256) ((float*)h_s)[i] = 0.f;
  const int u = j & 63, rg = j >> 6;
  float c[4] = {0.f,0.f,0.f,0.f};
  __syncthreads();
  for (int t = 0; t < steps; t++) {
    const float* xwt = XW + ((size_t)t*N + r0)*256;
    #pragma unroll 4
    for (int r = 0; r < 16; r++) {
      float acc = bj + xwt[r*256 + j];
      const float4* h4 = (const float4*)h_s[r];
      #pragma unroll
      for (int k4 = 0; k4 < 16; k4++) {
        float4 hv = h4[k4];
        acc += hv.x*w[4*k4+0] + hv.y*w[4*k4+1] + hv.z*w[4*k4+2] + hv.w*w[4*k4+3];
      }
      gates[r][j] = acc;
    }
    __syncthreads();
    #pragma unroll
    for (int q = 0; q < 4; q++) {
      const int r = rg*4 + q;
      float gi = gates[r][u], gf = gates[r][64+u], gg = gates[r][128+u], go = gates[r][192+u];
      float cv = sigm(gf)*c[q] + sigm(gi)*tanhe(gg);
      c[q] = cv;
      float hv = sigm(go)*tanhe(cv);
      h_s[r][u] = hv;
      if (h_all) h_all[((size_t)t*N + r0 + r)*64 + u] = hv;
    }
    __syncthreads();
  }
  if (h_final) {
    #pragma unroll
    for (int q = 0; q < 4; q++) {
      const int r = rg*4 + q;
      h_final[((size_t)r0 + r)*64 + u] = h_s[r][u];
    }
  }
}

// ---------------- single-step LSTM H=64 (enc) ----------------
__global__ __launch_bounds__(256) void lstm64_step_k(const float* __restrict__ XW, const float* __restrict__ Whh,
    const float* __restrict__ bih, const float* __restrict__ bhh,
    float* __restrict__ hstate, float* __restrict__ cstate, int t) {
  __shared__ __align__(16) float h_s[16][64];
  __shared__ __align__(16) float gates[16][256];
  const int j = threadIdx.x;
  const int r0 = blockIdx.x * 16;
  float w[64];
  #pragma unroll
  for (int k = 0; k < 64; k++) w[k] = Whh[(size_t)j*64 + k];
  const float bj = bih[j] + bhh[j];
  if (t == 0) {
    for (int i = j; i < 16*64; i += 256) ((float*)h_s)[i] = 0.f;
  } else {
    for (int i = j; i < 16*64; i += 256) ((float*)h_s)[i] = hstate[(size_t)r0*64 + i];
  }
  const int u = j & 63, rg = j >> 6;
  float c[4];
  #pragma unroll
  for (int q = 0; q < 4; q++) c[q] = (t == 0) ? 0.f : cstate[((size_t)r0 + rg*4 + q)*64 + u];
  __syncthreads();
  #pragma unroll 4
  for (int r = 0; r < 16; r++) {
    float acc = bj + XW[((size_t)r0 + r)*256 + j];
    const float4* h4 = (const float4*)h_s[r];
    #pragma unroll
    for (int k4 = 0; k4 < 16; k4++) {
      float4 hv = h4[k4];
      acc += hv.x*w[4*k4+0] + hv.y*w[4*k4+1] + hv.z*w[4*k4+2] + hv.w*w[4*k4+3];
    }
    gates[r][j] = acc;
  }
  __syncthreads();
  #pragma unroll
  for (int q = 0; q < 4; q++) {
    const int r = rg*4 + q;
    float gi = gates[r][u], gf = gates[r][64+u], gg = gates[r][128+u], go = gates[r][192+u];
    float cv = sigm(gf)*c[q] + sigm(gi)*tanhe(gg);
    float hv = sigm(go)*tanhe(cv);
    cstate[((size_t)r0 + r)*64 + u] = cv;
    hstate[((size_t)r0 + r)*64 + u] = hv;
  }
}

// ---------------- fused LSTM H=128 (dec; constant x) ----------------
__global__ __launch_bounds__(512) void lstm128_k(const float* __restrict__ XW, const float* __restrict__ Whh,
    const float* __restrict__ bih, const float* __restrict__ bhh, int N, int steps,
    float* __restrict__ h_all) {
  __shared__ __align__(16) float h_s[8][128];
  __shared__ __align__(16) float gates[8][512];
  const int j = threadIdx.x;
  const int r0 = blockIdx.x * 8;
  float w[128];
  #pragma unroll
  for (int k = 0; k < 128; k++) w[k] = Whh[(size_t)j*128 + k];
  const float bj = bih[j] + bhh[j];
  float xr[8];
  #pragma unroll
  for (int r = 0; r < 8; r++) xr[r] = XW[((size_t)r0 + r)*512 + j] + bj;
  for (int i = j; i < 8*128; i += 512) ((float*)h_s)[i] = 0.f;
  const int u = j & 127, rg = j >> 7;
  float c[2] = {0.f, 0.f};
  __syncthreads();
  for (int t = 0; t < steps; t++) {
    #pragma unroll 2
    for (int r = 0; r < 8; r++) {
      float acc = xr[r];
      const float4* h4 = (const float4*)h_s[r];
      #pragma unroll
      for (int k4 = 0; k4 < 32; k4++) {
        float4 hv = h4[k4];
        acc += hv.x*w[4*k4+0] + hv.y*w[4*k4+1] + hv.z*w[4*k4+2] + hv.w*w[4*k4+3];
      }
      gates[r][j] = acc;
    }
    __syncthreads();
    #pragma unroll
    for (int q = 0; q < 2; q++) {
      const int r = rg*2 + q;
      float gi = gates[r][u], gf = gates[r][128+u], gg = gates[r][256+u], go = gates[r][384+u];
      float cv = sigm(gf)*c[q] + sigm(gi)*tanhe(gg);
      c[q] = cv;
      float hv = sigm(go)*tanhe(cv);
      h_s[r][u] = hv;
      h_all[((size_t)t*N + r0 + r)*128 + u] = hv;
    }
    __syncthreads();
  }
}

// ---------------- temporal attention ----------------
__global__ __launch_bounds__(256) void ta_scores_k(const float* __restrict__ hs, const float* __restrict__ W,
                                                   const float* __restrict__ bias, float* __restrict__ sc) {
  int idx = blockIdx.x*256 + threadIdx.x;              // NBATCH*16
  int i = idx & 15; int b = idx >> 4;
  float acc = bias[i];
  for (int t = 0; t < 16; t++) {
    const float* hr = hs + ((size_t)t*NBATCH + b)*64;
    const float* wr = W + (size_t)i*1024 + t*64;
    #pragma unroll
    for (int h = 0; h < 64; h++) acc += hr[h]*wr[h];
  }
  sc[idx] = fmaxf(acc, 0.f);
}

__global__ __launch_bounds__(256) void ta_ctx_k(const float* __restrict__ hs, const float* __restrict__ sc,
    const float* __restrict__ dynW, const float* __restrict__ dynb, float* __restrict__ henc) {
  int idx = blockIdx.x*256 + threadIdx.x;              // NBATCH*32
  int o = idx & 31; int b = idx >> 5;
  const float* s = sc + (size_t)b*16;
  float m = s[0];
  #pragma unroll
  for (int t = 1; t < 16; t++) m = fmaxf(m, s[t]);
  float e[16]; float den = 0.f;
  #pragma unroll
  for (int t = 0; t < 16; t++) { e[t] = __expf(s[t]-m); den += e[t]; }
  float inv = 1.f/den;
  float acc = dynb[o];
  for (int t = 0; t < 16; t++) {
    const float* hr = hs + ((size_t)t*NBATCH + b)*64;
    float inner = 0.f;
    #pragma unroll
    for (int h = 0; h < 64; h++) inner += hr[h]*dynW[(size_t)o*64 + h];
    acc += (e[t]*inv)*inner;
  }
  henc[idx] = lr01(acc);
}

// ---------------- social conv path ----------------
__global__ __launch_bounds__(256) void repack_k(const float* __restrict__ scW, const float* __restrict__ c31W,
                                                float* __restrict__ wp1, float* __restrict__ wp2) {
  int idx = blockIdx.x*256 + threadIdx.x;              // 12288 + 3072
  if (idx < 12288) {
    int i = idx & 63; int r = idx >> 6; int kh = r % 3; int o = r / 3;
    wp1[idx] = scW[((size_t)(o*64+i)*3 + kh)*3];
  } else {
    int x2 = idx - 12288;
    int i = x2 & 63; int r = x2 >> 6; int kh = r % 3; int o = r / 3;
    wp2[x2] = c31W[(size_t)(o*64+i)*3 + kh];
  }
}

__global__ __launch_bounds__(256) void conv1_k(const float* __restrict__ nenc, const float* __restrict__ wp1,
                                               const float* __restrict__ bias, float* __restrict__ out) {
  size_t idx = (size_t)blockIdx.x*256 + threadIdx.x;   // NBATCH*64*11
  int h = (int)(idx % 11);
  size_t bo = idx / 11;
  int o = (int)(bo & 63);
  int b = (int)(bo >> 6);
  float acc = bias[o];
  for (int kh = 0; kh < 3; kh++) {
    int cc = h + kh;
    if (cc < 12) {
      const float* r = nenc + ((size_t)b*12 + cc)*64;
      const float* w = wp1 + ((size_t)o*3 + kh)*64;
      #pragma unroll
      for (int i = 0; i < 64; i++) acc += r[i]*w[i];
    }
  }
  out[idx] = lr01(acc);
}

__global__ __launch_bounds__(256) void conv2_k(const float* __restrict__ c1, const float* __restrict__ wp2,
                                               const float* __restrict__ bias, float* __restrict__ out) {
  size_t idx = (size_t)blockIdx.x*256 + threadIdx.x;   // NBATCH*16*9
  int h = (int)(idx % 9);
  size_t bo = idx / 9;
  int o = (int)(bo & 15);
  int b = (int)(bo >> 4);
  float acc = bias[o];
  for (int kh = 0; kh < 3; kh++) {
    const float* w = wp2 + ((size_t)o*3 + kh)*64;
    const float* base = c1 + (size_t)b*64*11 + (h+kh);
    #pragma unroll
    for (int i = 0; i < 64; i++) acc += base[i*11]*w[i];
  }
  out[idx] = lr01(acc);
}

// pool (pad 1, w=2 s=2 over 9 -> 5) + build enc(192) f32 and encd(197) bf16
__global__ __launch_bounds__(256) void pool_enc_k(const float* __restrict__ cv2, const float* __restrict__ henc,
    const float* __restrict__ lat_enc, const float* __restrict__ lon_enc,
    float* __restrict__ e192, bf16* __restrict__ encd) {
  int idx = blockIdx.x*256 + threadIdx.x;              // NBATCH*197
  int k = idx % 197; int b = idx / 197;
  float val;
  if (k < 192) {
    if (k < 160) {
      bool is_av = (k >= 80);
      int rel = is_av ? (k - 80) : k;
      int o = rel / 5, p = rel - o*5;
      const float* r = cv2 + ((size_t)b*16 + o)*9;
      float v2 = r[2*p];
      if (p == 0) val = is_av ? v2*0.5f : v2;
      else { float v1 = r[2*p-1]; val = is_av ? (v1+v2)*0.5f : fmaxf(v1, v2); }
    } else {
      val = henc[(size_t)b*32 + (k-160)];
    }
    e192[(size_t)b*192 + k] = val;
  } else if (k < 195) {
    val = lat_enc[(size_t)b*3 + (k-192)];
  } else {
    val = lon_enc[(size_t)b*2 + (k-195)];
  }
  encd[(size_t)b*197 + k] = fbf(val);
}

// ---------------- output heads ----------------
__global__ __launch_bounds__(256) void latlon_k(const float* __restrict__ e192,
    const float* __restrict__ latW, const float* __restrict__ latb,
    const float* __restrict__ lonW, const float* __restrict__ lonb,
    void* __restrict__ out, const int* __restrict__ flag) {
  int b = blockIdx.x*256 + threadIdx.x;                // NBATCH
  const int isf = *flag;
  const float* e = e192 + (size_t)b*192;
  float s[3];
  #pragma unroll
  for (int c2 = 0; c2 < 3; c2++) {
    float acc = latb[c2];
    for (int k = 0; k < 192; k++) acc += e[k]*latW[c2*192+k];
    s[c2] = acc;
  }
  float m = fmaxf(s[0], fmaxf(s[1], s[2]));
  float e0 = __expf(s[0]-m), e1 = __expf(s[1]-m), e2 = __expf(s[2]-m);
  float inv = 1.f/(e0+e1+e2);
  stout(out, isf, 256000 + (size_t)b*3 + 0, e0*inv);
  stout(out, isf, 256000 + (size_t)b*3 + 1, e1*inv);
  stout(out, isf, 256000 + (size_t)b*3 + 2, e2*inv);
  float q[2];
  #pragma unroll
  for (int c2 = 0; c2 < 2; c2++) {
    float acc = lonb[c2];
    for (int k = 0; k < 192; k++) acc += e[k]*lonW[c2*192+k];
    q[c2] = acc;
  }
  float m2 = fmaxf(q[0], q[1]);
  float f0 = __expf(q[0]-m2), f1 = __expf(q[1]-m2);
  float inv2 = 1.f/(f0+f1);
  stout(out, isf, 262144 + (size_t)b*2 + 0, f0*inv2);
  stout(out, isf, 262144 + (size_t)b*2 + 1, f1*inv2);
}

__global__ __launch_bounds__(256) void out_k(const float* __restrict__ hs2, const float* __restrict__ opW,
                                             const float* __restrict__ opb,
                                             void* __restrict__ out, const int* __restrict__ flag) {
  int idx = blockIdx.x*256 + threadIdx.x;              // NTOUT*NBATCH
  const int isf = *flag;
  const float* h = hs2 + (size_t)idx*128;
  float f[5];
  #pragma unroll
  for (int c2 = 0; c2 < 5; c2++) {
    float acc = opb[c2];
    #pragma unroll
    for (int k = 0; k < 128; k++) acc += h[k]*opW[c2*128+k];
    f[c2] = acc;
  }
  stout(out, isf, (size_t)idx*5 + 0, f[0]);
  stout(out, isf, (size_t)idx*5 + 1, f[1]);
  stout(out, isf, (size_t)idx*5 + 2, __expf(f[2]));
  stout(out, isf, (size_t)idx*5 + 3, __expf(f[3]));
  stout(out, isf, (size_t)idx*5 + 4, tanhe(f[4]));
}

// ---------------- workspace layout (f32-slot offsets) ----------------
static const size_t OFF_H2   = 0;           // bf16 x 13,631,488 (6,815,744 slots)
static const size_t OFF_P    = 6815744;     // 13,631,488 slots
static const size_t OFF_Q    = 20447232;    // 13,631,488 slots
static const size_t OFF_ESED = 34078720;    // 851,968
static const size_t OFF_ALPH = 34930688;    // 1,310,720 -> end 36,241,408
static const size_t OFF_XWTA = 6815744;     // 8,388,608 (over dead P)
static const size_t OFF_HS2  = 6815744;     // 6,553,600 (over dead XWTA, later)
static const size_t OFF_HSTA = 15204352;    // 2,097,152
static const size_t OFF_SCO  = 17301504;    // 32,768
static const size_t OFF_HEN  = 17334272;    // 65,536
static const size_t OFF_XWT  = 17399808;    // 6,291,456
static const size_t OFF_HST  = 23691264;    // 1,572,864
static const size_t OFF_CST  = 25264128;    // 1,572,864
static const size_t OFF_CV1  = 26836992;    // 1,441,792
static const size_t OFF_CV2  = 28278784;    // 294,912
static const size_t OFF_E192 = 28573696;    // 393,216
static const size_t OFF_ENCD = 28966912;    // 201,728 slots (bf16 x 403,456)
static const size_t OFF_XWD  = 29168640;    // 1,048,576
static const size_t OFF_WP1  = 30217216;    // 12,288
static const size_t OFF_WP2  = 30229504;    // 3,072
static const size_t OFF_CVT  = 36241408;    // converted f32 inputs (~5.04M)
static const size_t OFF_FLAG = 41400000;    // int flag; total ~165.6 MB

extern "C" void kernel_launch(void* const* d_in, const int* in_sizes, int n_in,
                              void* d_out, int out_size, void* d_ws, size_t ws_size,
                              hipStream_t stream) {
  (void)in_sizes; (void)n_in; (void)out_size; (void)ws_size;
  float* ws = (float*)d_ws;
  int* flag = (int*)(ws + OFF_FLAG);

  // ---- dtype detect + convert all float inputs to f32 arena ----
  static const int   cidx[NCVT] = {0,3,4,5,6,7,8,9,10,12,13,
    14,15,16,17,18,19,20,21,22,23,24,25,26,27,28,29,30,31,
    32,33,34,35,36,37,38,39,40,41,42,43,44,45,46,47,
    48,49,50,51,52,53,54,55,56,57};
  static const unsigned ccnt[NCVT] = {1703936,65536,65536,32768,65536,786432,786432,393216,786432,6144,4096,
    128,32,2048,64,64,64,2048,32,32,32,64,32,64,32,16,16,64,32,
    36864,16384,256,256,36864,16384,256,256,16384,16,2048,32,36864,64,3072,16,
    100864,65536,512,512,640,5,576,3,384,2};
  CvtArgs ca;
  unsigned total = 0;
  float* cp[58];
  for (int i = 0; i < NCVT; i++) {
    ca.src[i] = d_in[cidx[i]];
    ca.off[i] = total;
    ca.cnt[i] = ccnt[i];
    cp[cidx[i]] = ws + OFF_CVT + total;
    total += ccnt[i];
  }
  detect_k<<<1,256,0,stream>>>((const uint32_t*)d_in[0], flag);
  cvt_k<<<4096,256,0,stream>>>(ca, ws + OFF_CVT, flag, total);

  void* out = d_out;
  bf16*  h2    = (bf16*)(ws + OFF_H2);
  bf16*  h0    = (bf16*)(ws + OFF_P);
  bf16*  h1    = (bf16*)(ws + OFF_P);
  bf16*  xw1   = (bf16*)(ws + OFF_Q);
  bf16*  xw2   = (bf16*)(ws + OFF_Q);
  float* esed  = ws + OFF_ESED;
  float* alph  = ws + OFF_ALPH;
  float* xwta  = ws + OFF_XWTA;
  float* hsta  = ws + OFF_HSTA;
  float* sco   = ws + OFF_SCO;
  float* henc  = ws + OFF_HEN;
  float* xwt   = ws + OFF_XWT;
  float* hst   = ws + OFF_HST;
  float* cst   = ws + OFF_CST;
  float* cv1   = ws + OFF_CV1;
  float* cv2   = ws + OFF_CV2;
  float* e192  = ws + OFF_E192;
  bf16*  encd  = (bf16*)(ws + OFF_ENCD);
  float* xwd   = ws + OFF_XWD;
  float* wp1   = ws + OFF_WP1;
  float* wp2   = ws + OFF_WP2;
  float* hs2   = ws + OFF_HS2;

  // ---- GAT over 13-node star groups ----
  ip_emb_k<<<53248,256,0,stream>>>(cp[0], cp[14], cp[15], h0);
  dense_bf_k<32,64><<<106496,256,0,stream>>>(h0, cp[16], xw1);
  esed_bf_k<64><<<1664,256,0,stream>>>(xw1, cp[17], cp[18], esed);
  alpha_k<<<128,256,0,stream>>>(esed, alph);
  agg_bf_k<64><<<106496,256,0,stream>>>(xw1, alph, cp[19], h1);
  dense_bf_k<64,32><<<53248,256,0,stream>>>(h1, cp[20], xw2);
  esed_bf_k<32><<<1664,256,0,stream>>>(xw2, cp[21], cp[22], esed);
  alpha_k<<<128,256,0,stream>>>(esed, alph);
  agg_bf_k<32><<<53248,256,0,stream>>>(xw2, alph, cp[23], h2);

  // ---- temporal-attention branch ----
  gemm_embed_k<false><<<dim3(256,2),256,0,stream>>>(cp[3], cp[4], cp[5], cp[6], h2,
      cp[24],cp[25],cp[26],cp[27],cp[28],cp[29],cp[30],cp[31], cp[36], xwta, 0);
  lstm64_k<<<128,256,0,stream>>>(xwta, cp[37], cp[38], cp[39], NBATCH, TSEQ, hsta, nullptr);
  ta_scores_k<<<128,256,0,stream>>>(hsta, cp[40], cp[41], sco);
  ta_ctx_k<<<256,256,0,stream>>>(hsta, sco, cp[42], cp[43], henc);

  // ---- enc LSTM over neighbors: per-timestep fused-embed GEMM + recurrent step ----
  for (int t = 0; t < TSEQ; t++) {
    gemm_embed_k<true><<<dim3(192,2),256,0,stream>>>(cp[7], cp[8], cp[9], cp[10], h2,
        cp[24],cp[25],cp[26],cp[27],cp[28],cp[29],cp[30],cp[31], cp[32], xwt, t);
    lstm64_step_k<<<1536,256,0,stream>>>(xwt, cp[33], cp[34], cp[35], hst, cst, t);
  }

  // ---- social conv path ----
  repack_k<<<60,256,0,stream>>>(cp[44], cp[46], wp1, wp2);
  conv1_k<<<5632,256,0,stream>>>(hst, wp1, cp[45], cv1);
  conv2_k<<<1152,256,0,stream>>>(cv1, wp2, cp[47], cv2);
  pool_enc_k<<<1576,256,0,stream>>>(cv2, henc, cp[12], cp[13], e192, encd);

  // ---- heads ----
  latlon_k<<<8,256,0,stream>>>(e192, cp[54], cp[55], cp[56], cp[57], out, flag);
  gemm_bt<<<dim3(16,4),256,0,stream>>>(encd, cp[48], xwd, NBATCH, 512, 197);
  lstm128_k<<<256,512,0,stream>>>(xwd, cp[49], cp[50], cp[51], NBATCH, NTOUT, hs2);
  out_k<<<200,256,0,stream>>>(hs2, cp[52], cp[53], out, flag);
}